// Round 1
// baseline (578.037 us; speedup 1.0000x reference)
//
#include <hip/hip_runtime.h>

#define Bc    16
#define Vc    20
#define MFc   32
#define MTc   8
#define NPc   4
#define Kc    3
#define Rc    12
#define Dc    128
#define NOUTc 64

// block: 256 threads (4 waves). grid: (B*V, SPLIT).
// Each block handles MT*MF/SPLIT units (one (b,v) slice); each wave handles
// UNITS_PER_WAVE consecutive units and accumulates the (t,f)-sum in registers.
#define SPLIT 4
#define UNITS_PER_BLOCK (MTc * MFc / SPLIT)   // 64
#define UNITS_PER_WAVE  (UNITS_PER_BLOCK / 4) // 16

__global__ __launch_bounds__(256)
void gal_kernel(const float* __restrict__ src,    // [B,V,MT,MF,D]
                const float* __restrict__ rel,    // [B,V,MF,MT,NP,K,R]
                const float* __restrict__ W_rel,  // [R,D,D] (only diagonal used)
                const float* __restrict__ attn_w, // [NOUT+D]
                const float* __restrict__ out_w,  // [D,NOUT]
                const float* __restrict__ out_b,  // [NOUT]
                float* __restrict__ out)          // [B,V,NOUT]
{
    __shared__ float ow_lds[Dc * NOUTc];  // 32 KB
    const int tid  = threadIdx.x;
    const int lane = tid & 63;
    const int wv   = tid >> 6;
    const int bv   = blockIdx.x;          // 0..B*V-1

    // stage out_w into LDS (coalesced float loads)
    for (int i = tid; i < Dc * NOUTc; i += 256) ow_lds[i] = out_w[i];

    // per-lane register caches: diag[r][lane], diag[r][lane+64]
    float diag0[Rc], diag1[Rc];
#pragma unroll
    for (int r = 0; r < Rc; ++r) {
        diag0[r] = W_rel[r * Dc * Dc + lane * (Dc + 1)];
        diag1[r] = W_rel[r * Dc * Dc + (lane + 64) * (Dc + 1)];
    }
    const float aw0 = attn_w[NOUTc + lane];
    const float aw1 = attn_w[NOUTc + lane + 64];
    const float ob  = out_b[lane];

    __syncthreads();

    float out_acc = 0.f;
    const int u0 = blockIdx.y * UNITS_PER_BLOCK + wv * UNITS_PER_WAVE;

    for (int i = 0; i < UNITS_PER_WAVE; ++i) {
        const int u = u0 + i;
        const int t = u >> 5;   // u / MF
        const int f = u & 31;   // u % MF

        // wave-uniform rel_index base; force SGPR so loads scalarize
        const int xoff =
            __builtin_amdgcn_readfirstlane(((bv * MFc + f) * MTc + t) * (NPc * Kc * Rc));
        const float* __restrict__ x  = rel + xoff;
        const float* __restrict__ sp = src + ((bv * MTc + t) * MFc + f) * Dc;
        const float s0 = sp[lane];
        const float s1 = sp[lane + 64];

        float zj0[NPc], zj1[NPc], lg[NPc];
#pragma unroll
        for (int p = 0; p < NPc; ++p) {
            float w0 = 1.f, w1 = 1.f;
#pragma unroll
            for (int k = 0; k < Kc; ++k) {
                float a0 = 0.f, a1 = 0.f;
#pragma unroll
                for (int r = 0; r < Rc; ++r) {
                    const float xr = x[(p * Kc + k) * Rc + r];  // uniform -> s_load
                    a0 = fmaf(xr, diag0[r], a0);
                    a1 = fmaf(xr, diag1[r], a1);
                }
                w0 *= a0;
                w1 *= a1;
            }
            zj0[p] = w0 * s0;
            zj1[p] = w1 * s1;
            lg[p]  = zj0[p] * aw0 + zj1[p] * aw1;  // per-lane partial logit
        }

        // butterfly reduce the 4 logits across the wave
#pragma unroll
        for (int off = 32; off > 0; off >>= 1) {
#pragma unroll
            for (int p = 0; p < NPc; ++p) lg[p] += __shfl_xor(lg[p], off, 64);
        }

        // softmax over NP=4 (the uniform s-dot + bias terms cancel exactly)
        const float m  = fmaxf(fmaxf(lg[0], lg[1]), fmaxf(lg[2], lg[3]));
        const float e0 = __expf(lg[0] - m), e1 = __expf(lg[1] - m);
        const float e2 = __expf(lg[2] - m), e3 = __expf(lg[3] - m);
        const float inv = 1.f / (e0 + e1 + e2 + e3);
        const float a0 = e0 * inv, a1 = e1 * inv, a2 = e2 * inv, a3 = e3 * inv;

        const float z0 = a0 * zj0[0] + a1 * zj0[1] + a2 * zj0[2] + a3 * zj0[3];
        const float z1 = a0 * zj1[0] + a1 * zj1[1] + a2 * zj1[2] + a3 * zj1[3];

        // epilogue GEMV: lane n computes out[n] = sum_d z[d]*out_w[d][n]
        // z broadcast via readlane (compile-time lane index), out_w from LDS
        float o = ob;
#pragma unroll
        for (int d = 0; d < 64; ++d) {
            const float zd = __shfl(z0, d, 64);
            o = fmaf(zd, ow_lds[d * NOUTc + lane], o);
        }
#pragma unroll
        for (int d = 0; d < 64; ++d) {
            const float zd = __shfl(z1, d, 64);
            o = fmaf(zd, ow_lds[(d + 64) * NOUTc + lane], o);
        }
        out_acc += fmaxf(o, 0.f);
    }

    atomicAdd(&out[bv * NOUTc + lane], out_acc);
}

extern "C" void kernel_launch(void* const* d_in, const int* in_sizes, int n_in,
                              void* d_out, int out_size, void* d_ws, size_t ws_size,
                              hipStream_t stream) {
    const float* src    = (const float*)d_in[0];  // source_embed
    const float* rel    = (const float*)d_in[1];  // rel_index
    // d_in[2] = s        (cancels in softmax)
    const float* W_rel  = (const float*)d_in[3];
    const float* attn_w = (const float*)d_in[4];
    // d_in[5] = attn_b   (cancels in softmax)
    const float* out_w  = (const float*)d_in[6];
    const float* out_b  = (const float*)d_in[7];
    float* out = (float*)d_out;

    hipMemsetAsync(out, 0, (size_t)out_size * sizeof(float), stream);
    dim3 grid(Bc * Vc, SPLIT);
    gal_kernel<<<grid, 256, 0, stream>>>(src, rel, W_rel, attn_w, out_w, out_b, out);
}

// Round 2
// 482.073 us; speedup vs baseline: 1.1991x; 1.1991x over previous
//
#include <hip/hip_runtime.h>

#define Bc    16
#define Vc    20
#define MFc   32
#define MTc   8
#define NPc   4
#define Kc    3
#define Rc    12
#define Dc    128
#define NOUTc 64

// grid: (B*V, SPLIT). block: 256 threads (4 waves).
// Each wave handles UNITS_PER_WAVE consecutive (f,t) units; unit index
// u = f*MT + t so a wave's units are CONTIGUOUS in rel_index memory.
#define SPLIT 16
#define UNITS_PER_BLOCK (MTc * MFc / SPLIT)    // 16
#define UNITS_PER_WAVE  (UNITS_PER_BLOCK / 4)  // 4

__global__ __launch_bounds__(256, 4)
void gal_kernel(const float* __restrict__ src,    // [B,V,MT,MF,D]
                const float* __restrict__ rel,    // [B,V,MF,MT,NP,K,R]
                const float* __restrict__ W_rel,  // [R,D,D] (only diagonal used)
                const float* __restrict__ attn_w, // [NOUT+D]
                const float* __restrict__ out_w,  // [D,NOUT]
                const float* __restrict__ out_b,  // [NOUT]
                float* __restrict__ out)          // [B,V,NOUT]
{
    // ow4[dq*64+n] = {W[4dq+0][n], W[4dq+1][n], W[4dq+2][n], W[4dq+3][n]}
    __shared__ float4 ow4[(Dc / 4) * NOUTc];   // 32 KB
    __shared__ float  zbuf[4][Dc];             // 2 KB, per-wave z scratch

    const int tid  = threadIdx.x;
    const int lane = tid & 63;
    const int wv   = tid >> 6;
    const int bv   = blockIdx.x;

    // stage out_w into LDS in quad-transposed layout (coalesced: each 64-thread
    // subgroup reads a contiguous 64-float row of out_w per component)
    for (int e = tid; e < (Dc / 4) * NOUTc; e += 256) {
        const int dq = e >> 6, n = e & 63;
        ow4[e] = make_float4(out_w[(4 * dq + 0) * NOUTc + n],
                             out_w[(4 * dq + 1) * NOUTc + n],
                             out_w[(4 * dq + 2) * NOUTc + n],
                             out_w[(4 * dq + 3) * NOUTc + n]);
    }

    // per-lane register caches of the W_rel diagonals
    float diag0[Rc], diag1[Rc];
#pragma unroll
    for (int r = 0; r < Rc; ++r) {
        diag0[r] = W_rel[r * Dc * Dc + lane * (Dc + 1)];
        diag1[r] = W_rel[r * Dc * Dc + (lane + 64) * (Dc + 1)];
    }
    const float aw0 = attn_w[NOUTc + lane];
    const float aw1 = attn_w[NOUTc + lane + 64];
    const float ob  = out_b[lane];

    __syncthreads();

    float out_acc = 0.f;
    const int u0 = blockIdx.y * UNITS_PER_BLOCK + wv * UNITS_PER_WAVE;

    for (int i = 0; i < UNITS_PER_WAVE; ++i) {
        const int u = u0 + i;
        const int t = u & (MTc - 1);   // u % MT  (fast axis -> rel contiguous)
        const int f = u >> 3;          // u / MT

        // wave-uniform rel_index base; readfirstlane forces scalar loads
        const int xoff =
            __builtin_amdgcn_readfirstlane(((bv * MFc + f) * MTc + t) * (NPc * Kc * Rc));
        const float* __restrict__ x  = rel + xoff;
        const float* __restrict__ sp = src + ((bv * MTc + t) * MFc + f) * Dc;
        const float s0 = sp[lane];
        const float s1 = sp[lane + 64];

        float zj0[NPc], zj1[NPc], lg[NPc];
#pragma unroll
        for (int p = 0; p < NPc; ++p) {
            float w0 = 1.f, w1 = 1.f;
#pragma unroll
            for (int k = 0; k < Kc; ++k) {
                float a0 = 0.f, a1 = 0.f;
#pragma unroll
                for (int r = 0; r < Rc; ++r) {
                    const float xr = x[(p * Kc + k) * Rc + r];  // s_load (uniform)
                    a0 = fmaf(xr, diag0[r], a0);
                    a1 = fmaf(xr, diag1[r], a1);
                }
                w0 *= a0;
                w1 *= a1;
            }
            zj0[p] = w0 * s0;
            zj1[p] = w1 * s1;
            lg[p]  = zj0[p] * aw0 + zj1[p] * aw1;  // per-lane partial logit
        }

        // butterfly-reduce the 4 logits across the wave
#pragma unroll
        for (int off = 32; off > 0; off >>= 1) {
#pragma unroll
            for (int p = 0; p < NPc; ++p) lg[p] += __shfl_xor(lg[p], off, 64);
        }

        // softmax over NP=4 (uniform s-dot + bias cancel exactly)
        const float m  = fmaxf(fmaxf(lg[0], lg[1]), fmaxf(lg[2], lg[3]));
        const float e0 = __expf(lg[0] - m), e1 = __expf(lg[1] - m);
        const float e2 = __expf(lg[2] - m), e3 = __expf(lg[3] - m);
        const float inv = 1.f / (e0 + e1 + e2 + e3);
        const float a0 = e0 * inv, a1 = e1 * inv, a2 = e2 * inv, a3 = e3 * inv;

        const float z0 = a0 * zj0[0] + a1 * zj0[1] + a2 * zj0[2] + a3 * zj0[3];
        const float z1 = a0 * zj1[0] + a1 * zj1[1] + a2 * zj1[2] + a3 * zj1[3];

        // broadcast z through per-wave LDS scratch (same-wave RAW: no barrier)
        zbuf[wv][lane]      = z0;
        zbuf[wv][lane + 64] = z1;
        const float4* zq = (const float4*)zbuf[wv];

        // epilogue GEMV: lane n computes out[n]; 4 independent FMA chains,
        // 32x ds_read_b128 (ow, conflict-free) + 32x ds_read_b128 (z, broadcast)
        float o0 = 0.f, o1 = 0.f, o2 = 0.f, o3 = 0.f;
#pragma unroll
        for (int dq = 0; dq < Dc / 4; ++dq) {
            const float4 w4 = ow4[dq * NOUTc + lane];
            const float4 z4 = zq[dq];
            o0 = fmaf(z4.x, w4.x, o0);
            o1 = fmaf(z4.y, w4.y, o1);
            o2 = fmaf(z4.z, w4.z, o2);
            o3 = fmaf(z4.w, w4.w, o3);
        }
        out_acc += fmaxf(ob + ((o0 + o1) + (o2 + o3)), 0.f);
    }

    // block-level reduction: 4 waves -> 1 atomic per block
    __syncthreads();               // zbuf reuse safety
    zbuf[wv][lane] = out_acc;
    __syncthreads();
    if (wv == 0) {
        const float tot = zbuf[0][lane] + zbuf[1][lane] + zbuf[2][lane] + zbuf[3][lane];
        atomicAdd(&out[bv * NOUTc + lane], tot);
    }
}

extern "C" void kernel_launch(void* const* d_in, const int* in_sizes, int n_in,
                              void* d_out, int out_size, void* d_ws, size_t ws_size,
                              hipStream_t stream) {
    const float* src    = (const float*)d_in[0];  // source_embed
    const float* rel    = (const float*)d_in[1];  // rel_index
    // d_in[2] = s        (cancels in softmax)
    const float* W_rel  = (const float*)d_in[3];
    const float* attn_w = (const float*)d_in[4];
    // d_in[5] = attn_b   (cancels in softmax)
    const float* out_w  = (const float*)d_in[6];
    const float* out_b  = (const float*)d_in[7];
    float* out = (float*)d_out;

    hipMemsetAsync(out, 0, (size_t)out_size * sizeof(float), stream);
    dim3 grid(Bc * Vc, SPLIT);
    gal_kernel<<<grid, 256, 0, stream>>>(src, rel, W_rel, attn_w, out_w, out_b, out);
}

// Round 3
// 144.478 us; speedup vs baseline: 4.0009x; 3.3367x over previous
//
#include <hip/hip_runtime.h>

#define Bc    16
#define Vc    20
#define MFc   32
#define MTc   8
#define NPc   4
#define Kc    3
#define Rc    12
#define Dc    128
#define NOUTc 64

// grid: (B*V, SPLIT). block: 256 threads (4 waves).
#define SPLIT 16
#define UNITS_PER_BLOCK (MTc * MFc / SPLIT)    // 16
#define UNITS_PER_WAVE  (UNITS_PER_BLOCK / 4)  // 4

// Setup: extract W_rel diagonals into contiguous diagT[d][r] (d-major so each
// lane's 12 r-values are 48 contiguous bytes -> 3x float4 loads).
__global__ void diag_extract(const float* __restrict__ W_rel,
                             float* __restrict__ diagT) {
    const int i = blockIdx.x * 256 + threadIdx.x;  // over R*D = 1536
    if (i < Rc * Dc) {
        const int d = i / Rc, r = i % Rc;
        diagT[i] = W_rel[r * Dc * Dc + d * (Dc + 1)];
    }
}

__global__ __launch_bounds__(256)
void gal_kernel(const float* __restrict__ src,    // [B,V,MT,MF,D]
                const float* __restrict__ rel,    // [B,V,MF,MT,NP,K,R]
                const float* __restrict__ diagT,  // [D,R] contiguous
                const float* __restrict__ attn_w, // [NOUT+D]
                const float* __restrict__ out_w,  // [D,NOUT]
                const float* __restrict__ out_b,  // [NOUT]
                float* __restrict__ out)          // [B,V,NOUT]
{
    // ow4[dq*64+n] = {W[4dq+0][n], W[4dq+1][n], W[4dq+2][n], W[4dq+3][n]}
    __shared__ float4 ow4[(Dc / 4) * NOUTc];   // 32 KB
    __shared__ float  zbuf[4][Dc];             // 2 KB, per-wave z scratch

    const int tid  = threadIdx.x;
    const int lane = tid & 63;
    const int wv   = tid >> 6;
    const int bv   = blockIdx.x;

    // stage out_w into LDS, quad-transposed
    for (int e = tid; e < (Dc / 4) * NOUTc; e += 256) {
        const int dq = e >> 6, n = e & 63;
        ow4[e] = make_float4(out_w[(4 * dq + 0) * NOUTc + n],
                             out_w[(4 * dq + 1) * NOUTc + n],
                             out_w[(4 * dq + 2) * NOUTc + n],
                             out_w[(4 * dq + 3) * NOUTc + n]);
    }

    // per-lane register caches of the W_rel diagonals (vectorized from diagT)
    float diag0[Rc], diag1[Rc];
    {
        const float4* dg0 = (const float4*)(diagT + lane * Rc);
        const float4* dg1 = (const float4*)(diagT + (lane + 64) * Rc);
#pragma unroll
        for (int q = 0; q < 3; ++q) {
            const float4 v0 = dg0[q], v1 = dg1[q];
            diag0[4 * q + 0] = v0.x; diag0[4 * q + 1] = v0.y;
            diag0[4 * q + 2] = v0.z; diag0[4 * q + 3] = v0.w;
            diag1[4 * q + 0] = v1.x; diag1[4 * q + 1] = v1.y;
            diag1[4 * q + 2] = v1.z; diag1[4 * q + 3] = v1.w;
        }
    }
    const float aw0 = attn_w[NOUTc + lane];
    const float aw1 = attn_w[NOUTc + lane + 64];
    const float ob  = out_b[lane];

    __syncthreads();

    float out_acc = 0.f;
    const int u0 = blockIdx.y * UNITS_PER_BLOCK + wv * UNITS_PER_WAVE;

    for (int i = 0; i < UNITS_PER_WAVE; ++i) {
        const int u = u0 + i;
        const int t = u & (MTc - 1);   // fast axis -> rel contiguous
        const int f = u >> 3;

        const int xoff =
            __builtin_amdgcn_readfirstlane(((bv * MFc + f) * MTc + t) * (NPc * Kc * Rc));
        const float* __restrict__ x  = rel + xoff;
        const float* __restrict__ sp = src + ((bv * MTc + t) * MFc + f) * Dc;
        const float s0 = sp[lane];
        const float s1 = sp[lane + 64];

        float zj0[NPc], zj1[NPc], lg[NPc];
#pragma unroll
        for (int p = 0; p < NPc; ++p) {
            float w0 = 1.f, w1 = 1.f;
#pragma unroll 1           // keep scalar x-loads from being hoisted en masse
            for (int k = 0; k < Kc; ++k) {
                float a0 = 0.f, a1 = 0.f;
#pragma unroll
                for (int r = 0; r < Rc; ++r) {
                    const float xr = x[(p * Kc + k) * Rc + r];  // s_load (uniform)
                    a0 = fmaf(xr, diag0[r], a0);
                    a1 = fmaf(xr, diag1[r], a1);
                }
                w0 *= a0;
                w1 *= a1;
            }
            zj0[p] = w0 * s0;
            zj1[p] = w1 * s1;
            lg[p]  = zj0[p] * aw0 + zj1[p] * aw1;
        }

        // butterfly-reduce the 4 logits across the wave
#pragma unroll
        for (int off = 32; off > 0; off >>= 1) {
#pragma unroll
            for (int p = 0; p < NPc; ++p) lg[p] += __shfl_xor(lg[p], off, 64);
        }

        // softmax over NP=4 (uniform s-dot + bias cancel exactly)
        const float m  = fmaxf(fmaxf(lg[0], lg[1]), fmaxf(lg[2], lg[3]));
        const float e0 = __expf(lg[0] - m), e1 = __expf(lg[1] - m);
        const float e2 = __expf(lg[2] - m), e3 = __expf(lg[3] - m);
        const float inv = 1.f / (e0 + e1 + e2 + e3);
        const float a0 = e0 * inv, a1 = e1 * inv, a2 = e2 * inv, a3 = e3 * inv;

        const float z0 = a0 * zj0[0] + a1 * zj0[1] + a2 * zj0[2] + a3 * zj0[3];
        const float z1 = a0 * zj1[0] + a1 * zj1[1] + a2 * zj1[2] + a3 * zj1[3];

        // broadcast z through per-wave LDS scratch (same-wave RAW: no barrier)
        zbuf[wv][lane]      = z0;
        zbuf[wv][lane + 64] = z1;
        const float4* zq = (const float4*)zbuf[wv];

        // epilogue GEMV: 4 independent FMA chains; ow4 reads conflict-free,
        // z reads are same-address broadcast (free)
        float o0 = 0.f, o1 = 0.f, o2 = 0.f, o3 = 0.f;
#pragma unroll
        for (int dq = 0; dq < Dc / 4; ++dq) {
            const float4 w4 = ow4[dq * NOUTc + lane];
            const float4 z4 = zq[dq];
            o0 = fmaf(z4.x, w4.x, o0);
            o1 = fmaf(z4.y, w4.y, o1);
            o2 = fmaf(z4.z, w4.z, o2);
            o3 = fmaf(z4.w, w4.w, o3);
        }
        out_acc += fmaxf(ob + ((o0 + o1) + (o2 + o3)), 0.f);
    }

    // block-level reduction: 4 waves -> 1 atomic per block
    __syncthreads();
    zbuf[wv][lane] = out_acc;
    __syncthreads();
    if (wv == 0) {
        const float tot = zbuf[0][lane] + zbuf[1][lane] + zbuf[2][lane] + zbuf[3][lane];
        atomicAdd(&out[bv * NOUTc + lane], tot);
    }
}

extern "C" void kernel_launch(void* const* d_in, const int* in_sizes, int n_in,
                              void* d_out, int out_size, void* d_ws, size_t ws_size,
                              hipStream_t stream) {
    const float* src    = (const float*)d_in[0];  // source_embed
    const float* rel    = (const float*)d_in[1];  // rel_index
    // d_in[2] = s        (cancels in softmax)
    const float* W_rel  = (const float*)d_in[3];
    const float* attn_w = (const float*)d_in[4];
    // d_in[5] = attn_b   (cancels in softmax)
    const float* out_w  = (const float*)d_in[6];
    const float* out_b  = (const float*)d_in[7];
    float* out   = (float*)d_out;
    float* diagT = (float*)d_ws;                  // R*D floats = 6 KB

    hipMemsetAsync(out, 0, (size_t)out_size * sizeof(float), stream);
    diag_extract<<<(Rc * Dc + 255) / 256, 256, 0, stream>>>(W_rel, diagT);
    dim3 grid(Bc * Vc, SPLIT);
    gal_kernel<<<grid, 256, 0, stream>>>(src, rel, diagT, attn_w, out_w, out_b, out);
}

// Round 4
// 100.403 us; speedup vs baseline: 5.7572x; 1.4390x over previous
//
#include <hip/hip_runtime.h>

#define Bc    16
#define Vc    20
#define MFc   32
#define MTc   8
#define NPc   4
#define Kc    3
#define Rc    12
#define Dc    128
#define NOUTc 64

// grid: (B*V, SPLIT). block: 256 threads (4 waves).
// Block processes UNITS_PER_BLOCK units in NGROUPS groups of 4 (1 unit/wave).
#define SPLIT 16
#define UNITS_PER_BLOCK (MTc * MFc / SPLIT)    // 16
#define NGROUPS (UNITS_PER_BLOCK / 4)          // 4

// Setup: extract W_rel diagonals into contiguous diagT[d][r].
__global__ void diag_extract(const float* __restrict__ W_rel,
                             float* __restrict__ diagT) {
    const int i = blockIdx.x * 256 + threadIdx.x;  // over R*D = 1536
    if (i < Rc * Dc) {
        const int d = i / Rc, r = i % Rc;
        diagT[i] = W_rel[r * Dc * Dc + d * (Dc + 1)];
    }
}

__global__ __launch_bounds__(256)
void gal_kernel(const float* __restrict__ src,    // [B,V,MT,MF,D]
                const float* __restrict__ rel,    // [B,V,MF,MT,NP,K,R]
                const float* __restrict__ diagT,  // [D,R] contiguous
                const float* __restrict__ attn_w, // [NOUT+D]
                const float* __restrict__ out_w,  // [D,NOUT]
                const float* __restrict__ out_b,  // [NOUT]
                float* __restrict__ out)          // [B,V,NOUT]
{
    __shared__ float zs[4][Dc];        // 2 KB: per-group z, row = unit slot
    __shared__ float po[16][NOUTc];    // 4 KB: GEMV partials [slot*4+wave][n]

    const int tid  = threadIdx.x;
    const int lane = tid & 63;
    const int wv   = tid >> 6;
    const int bv   = blockIdx.x;

    // out_w rows [32*wv, 32*wv+32) live in registers (lane = output column n)
    float Wreg[32];
#pragma unroll
    for (int j = 0; j < 32; ++j)
        Wreg[j] = out_w[(32 * wv + j) * NOUTc + lane];

    // W_rel diagonal caches (vectorized from contiguous diagT)
    float diag0[Rc], diag1[Rc];
    {
        const float4* dg0 = (const float4*)(diagT + lane * Rc);
        const float4* dg1 = (const float4*)(diagT + (lane + 64) * Rc);
#pragma unroll
        for (int q = 0; q < 3; ++q) {
            const float4 v0 = dg0[q], v1 = dg1[q];
            diag0[4 * q + 0] = v0.x; diag0[4 * q + 1] = v0.y;
            diag0[4 * q + 2] = v0.z; diag0[4 * q + 3] = v0.w;
            diag1[4 * q + 0] = v1.x; diag1[4 * q + 1] = v1.y;
            diag1[4 * q + 2] = v1.z; diag1[4 * q + 3] = v1.w;
        }
    }
    const float aw0 = attn_w[NOUTc + lane];
    const float aw1 = attn_w[NOUTc + lane + 64];
    const float ob  = out_b[lane];

    float out_acc = 0.f;
    const int u0 = blockIdx.y * UNITS_PER_BLOCK;

    for (int g = 0; g < NGROUPS; ++g) {
        // ---- P1: this wave's unit -> z (register), then 2 LDS writes ----
        const int u = u0 + g * 4 + wv;
        const int t = u & (MTc - 1);
        const int f = u >> 3;

        const int xoff =
            __builtin_amdgcn_readfirstlane(((bv * MFc + f) * MTc + t) * (NPc * Kc * Rc));
        const float* __restrict__ x  = rel + xoff;
        const float* __restrict__ sp = src + ((bv * MTc + t) * MFc + f) * Dc;
        const float s0 = sp[lane];
        const float s1 = sp[lane + 64];

        float zj0[NPc], zj1[NPc], lg[NPc];
#pragma unroll
        for (int p = 0; p < NPc; ++p) {
            float w0 = 1.f, w1 = 1.f;
#pragma unroll 1           // keep scalar x-loads from being hoisted en masse
            for (int k = 0; k < Kc; ++k) {
                float a0 = 0.f, a1 = 0.f;
#pragma unroll
                for (int r = 0; r < Rc; ++r) {
                    const float xr = x[(p * Kc + k) * Rc + r];  // s_load (uniform)
                    a0 = fmaf(xr, diag0[r], a0);
                    a1 = fmaf(xr, diag1[r], a1);
                }
                w0 *= a0;
                w1 *= a1;
            }
            zj0[p] = w0 * s0;
            zj1[p] = w1 * s1;
            lg[p]  = zj0[p] * aw0 + zj1[p] * aw1;
        }

#pragma unroll
        for (int off = 32; off > 0; off >>= 1) {
#pragma unroll
            for (int p = 0; p < NPc; ++p) lg[p] += __shfl_xor(lg[p], off, 64);
        }

        // softmax over NP=4 (uniform s-dot + bias cancel exactly)
        const float m  = fmaxf(fmaxf(lg[0], lg[1]), fmaxf(lg[2], lg[3]));
        const float e0 = __expf(lg[0] - m), e1 = __expf(lg[1] - m);
        const float e2 = __expf(lg[2] - m), e3 = __expf(lg[3] - m);
        const float inv = 1.f / (e0 + e1 + e2 + e3);
        const float a0 = e0 * inv, a1 = e1 * inv, a2 = e2 * inv, a3 = e3 * inv;

        zs[wv][lane]      = a0 * zj0[0] + a1 * zj0[1] + a2 * zj0[2] + a3 * zj0[3];
        zs[wv][lane + 64] = a0 * zj1[0] + a1 * zj1[1] + a2 * zj1[2] + a3 * zj1[3];

        __syncthreads();   // zs ready for all waves; po safe to overwrite

        // ---- P2: 32-row GEMV slice for all 4 units vs register W ----
#pragma unroll
        for (int uu = 0; uu < 4; ++uu) {
            const float4* zq = (const float4*)&zs[uu][32 * wv];  // broadcast reads
            float p0 = 0.f, p1 = 0.f, p2 = 0.f, p3 = 0.f;
#pragma unroll
            for (int q = 0; q < 8; ++q) {
                const float4 z4 = zq[q];
                p0 = fmaf(z4.x, Wreg[4 * q + 0], p0);
                p1 = fmaf(z4.y, Wreg[4 * q + 1], p1);
                p2 = fmaf(z4.z, Wreg[4 * q + 2], p2);
                p3 = fmaf(z4.w, Wreg[4 * q + 3], p3);
            }
            po[uu * 4 + wv][lane] = (p0 + p1) + (p2 + p3);
        }

        __syncthreads();   // po ready; zs safe to overwrite next group

        // ---- P3: wave wv finishes unit slot wv: sum partials + bias + relu ----
        const float v = po[wv * 4 + 0][lane] + po[wv * 4 + 1][lane]
                      + po[wv * 4 + 2][lane] + po[wv * 4 + 3][lane];
        out_acc += fmaxf(ob + v, 0.f);
    }

    // block reduction: 4 waves -> 1 atomic per block
    __syncthreads();
    po[wv][lane] = out_acc;
    __syncthreads();
    if (wv == 0) {
        const float tot = po[0][lane] + po[1][lane] + po[2][lane] + po[3][lane];
        atomicAdd(&out[bv * NOUTc + lane], tot);
    }
}

extern "C" void kernel_launch(void* const* d_in, const int* in_sizes, int n_in,
                              void* d_out, int out_size, void* d_ws, size_t ws_size,
                              hipStream_t stream) {
    const float* src    = (const float*)d_in[0];  // source_embed
    const float* rel    = (const float*)d_in[1];  // rel_index
    // d_in[2] = s        (cancels in softmax)
    const float* W_rel  = (const float*)d_in[3];
    const float* attn_w = (const float*)d_in[4];
    // d_in[5] = attn_b   (cancels in softmax)
    const float* out_w  = (const float*)d_in[6];
    const float* out_b  = (const float*)d_in[7];
    float* out   = (float*)d_out;
    float* diagT = (float*)d_ws;                  // R*D floats = 6 KB

    hipMemsetAsync(out, 0, (size_t)out_size * sizeof(float), stream);
    diag_extract<<<(Rc * Dc + 255) / 256, 256, 0, stream>>>(W_rel, diagT);
    dim3 grid(Bc * Vc, SPLIT);
    gal_kernel<<<grid, 256, 0, stream>>>(src, rel, diagT, attn_w, out_w, out_b, out);
}

// Round 5
// 93.242 us; speedup vs baseline: 6.1993x; 1.0768x over previous
//
#include <hip/hip_runtime.h>

#define Bc    16
#define Vc    20
#define MFc   32
#define MTc   8
#define NPc   4
#define Kc    3
#define Rc    12
#define Dc    128
#define NOUTc 64

#define TOTAL_UNITS (Bc * Vc * MTc * MFc)   // 81920 ; unit u = bv*256 + f*8 + t
#define XPU (NPc * Kc * Rc)                 // 144 floats of rel per unit
#define NBLOCKS 2048                        // 8 blocks/CU exactly, uniform work
#define UNITS_PER_BLOCK (TOTAL_UNITS / NBLOCKS)  // 40
#define NGROUPS (UNITS_PER_BLOCK / 4)            // 10

// Setup: extract W_rel diagonals into contiguous diagT[d][r].
__global__ void diag_extract(const float* __restrict__ W_rel,
                             float* __restrict__ diagT) {
    const int i = blockIdx.x * 256 + threadIdx.x;  // over R*D = 1536
    if (i < Rc * Dc) {
        const int d = i / Rc, r = i % Rc;
        diagT[i] = W_rel[r * Dc * Dc + d * (Dc + 1)];
    }
}

__global__ __launch_bounds__(256)
void gal_kernel(const float* __restrict__ src,    // [B,V,MT,MF,D]
                const float* __restrict__ rel,    // [B,V,MF,MT,NP,K,R] = [u][144]
                const float* __restrict__ diagT,  // [D,R] contiguous
                const float* __restrict__ attn_w, // [NOUT+D]
                const float* __restrict__ out_w,  // [D,NOUT]
                const float* __restrict__ out_b,  // [NOUT]
                float* __restrict__ out)          // [B,V,NOUT]
{
    __shared__ float zs[2][4][Dc];        // 4 KB: double-buffered per-group z
    __shared__ float po[2][16][NOUTc];    // 8 KB: double-buffered GEMV partials

    const int tid  = threadIdx.x;
    const int lane = tid & 63;
    const int wv   = tid >> 6;

    const int u_base = blockIdx.x * UNITS_PER_BLOCK;
    const int bv0    = u_base >> 8;       // 256 units per bv

    // out_w rows [32*wv, 32*wv+32) in registers (lane = output column n)
    float Wreg[32];
#pragma unroll
    for (int j = 0; j < 32; ++j)
        Wreg[j] = out_w[(32 * wv + j) * NOUTc + lane];

    // W_rel diagonal caches (vectorized from contiguous diagT)
    float diag0[Rc], diag1[Rc];
    {
        const float4* dg0 = (const float4*)(diagT + lane * Rc);
        const float4* dg1 = (const float4*)(diagT + (lane + 64) * Rc);
#pragma unroll
        for (int q = 0; q < 3; ++q) {
            const float4 v0 = dg0[q], v1 = dg1[q];
            diag0[4 * q + 0] = v0.x; diag0[4 * q + 1] = v0.y;
            diag0[4 * q + 2] = v0.z; diag0[4 * q + 3] = v0.w;
            diag1[4 * q + 0] = v1.x; diag1[4 * q + 1] = v1.y;
            diag1[4 * q + 2] = v1.z; diag1[4 * q + 3] = v1.w;
        }
    }
    const float aw0 = attn_w[NOUTc + lane];
    const float aw1 = attn_w[NOUTc + lane + 64];
    const float ob  = out_b[lane];

    float acc0 = 0.f, acc1 = 0.f;   // per-bv accumulators (block spans <=1 boundary)

    for (int g = 0; g < NGROUPS; ++g) {
        const int X = g & 1, Y = X ^ 1;

        // ---- L2-warming prefetch of NEXT group's rel chunk (2304 B contig) ----
        float4 pf = make_float4(0.f, 0.f, 0.f, 0.f);
        if (tid < 144) {
            int off = (u_base + (g + 1) * 4) * XPU + tid * 4;
            const int maxoff = TOTAL_UNITS * XPU - 4 * 144;
            if (off > maxoff) off = maxoff;
            pf = *(const float4*)(rel + off);
        }

        // ---- P1: this wave's unit -> z, write to zs[X] ----
        const int u   = u_base + g * 4 + wv;
        const int t   = u & (MTc - 1);
        const int f   = (u >> 3) & (MFc - 1);
        const int ubv = u >> 8;

        const int xoff = __builtin_amdgcn_readfirstlane(u * XPU);
        const float* __restrict__ x  = rel + xoff;   // wave-uniform -> s_load
        const float* __restrict__ sp = src + ((ubv * MTc + t) * MFc + f) * Dc;
        const float s0 = sp[lane];
        const float s1 = sp[lane + 64];

        float zj0[NPc], zj1[NPc], lg[NPc];
#pragma unroll
        for (int p = 0; p < NPc; ++p) {
            float w0 = 1.f, w1 = 1.f;
#pragma unroll 1           // keep scalar x-loads from being hoisted en masse
            for (int k = 0; k < Kc; ++k) {
                float a0 = 0.f, a1 = 0.f;
#pragma unroll
                for (int r = 0; r < Rc; ++r) {
                    const float xr = x[(p * Kc + k) * Rc + r];  // s_load (uniform)
                    a0 = fmaf(xr, diag0[r], a0);
                    a1 = fmaf(xr, diag1[r], a1);
                }
                w0 *= a0;
                w1 *= a1;
            }
            zj0[p] = w0 * s0;
            zj1[p] = w1 * s1;
            lg[p]  = zj0[p] * aw0 + zj1[p] * aw1;
        }

#pragma unroll
        for (int off = 32; off > 0; off >>= 1) {
#pragma unroll
            for (int p = 0; p < NPc; ++p) lg[p] += __shfl_xor(lg[p], off, 64);
        }

        // softmax over NP=4 (uniform s-dot + bias cancel exactly)
        const float m  = fmaxf(fmaxf(lg[0], lg[1]), fmaxf(lg[2], lg[3]));
        const float e0 = __expf(lg[0] - m), e1 = __expf(lg[1] - m);
        const float e2 = __expf(lg[2] - m), e3 = __expf(lg[3] - m);
        const float inv = 1.f / (e0 + e1 + e2 + e3);
        const float a0 = e0 * inv, a1 = e1 * inv, a2 = e2 * inv, a3 = e3 * inv;

        zs[X][wv][lane]      = a0 * zj0[0] + a1 * zj0[1] + a2 * zj0[2] + a3 * zj0[3];
        zs[X][wv][lane + 64] = a0 * zj1[0] + a1 * zj1[1] + a2 * zj1[2] + a3 * zj1[3];

        __syncthreads();   // zs[X] ready; po[X] free (last read before prev bar)

        // ---- P2(g): 32-row GEMV slice for all 4 units vs register W ----
#pragma unroll
        for (int uu = 0; uu < 4; ++uu) {
            const float4* zq = (const float4*)&zs[X][uu][32 * wv];  // broadcast
            float p0 = 0.f, p1 = 0.f, p2 = 0.f, p3 = 0.f;
#pragma unroll
            for (int q = 0; q < 8; ++q) {
                const float4 z4 = zq[q];
                p0 = fmaf(z4.x, Wreg[4 * q + 0], p0);
                p1 = fmaf(z4.y, Wreg[4 * q + 1], p1);
                p2 = fmaf(z4.z, Wreg[4 * q + 2], p2);
                p3 = fmaf(z4.w, Wreg[4 * q + 3], p3);
            }
            po[X][uu * 4 + wv][lane] = (p0 + p1) + (p2 + p3);
        }

        // ---- P3(g-1): finish previous group's unit slot wv (no barrier) ----
        if (g > 0) {
            const int up = u_base + (g - 1) * 4 + wv;
            const float v = po[Y][wv * 4 + 0][lane] + po[Y][wv * 4 + 1][lane]
                          + po[Y][wv * 4 + 2][lane] + po[Y][wv * 4 + 3][lane];
            const float rv = fmaxf(ob + v, 0.f);
            if ((up >> 8) == bv0) acc0 += rv; else acc1 += rv;
        }

        // consume prefetch late: waitcnt lands after a full group of compute
        asm volatile("" :: "v"(pf.x), "v"(pf.y), "v"(pf.z), "v"(pf.w));
    }

    // ---- final P3 for the last group ----
    __syncthreads();
    {
        const int XL = (NGROUPS - 1) & 1;
        const int up = u_base + (NGROUPS - 1) * 4 + wv;
        const float v = po[XL][wv * 4 + 0][lane] + po[XL][wv * 4 + 1][lane]
                      + po[XL][wv * 4 + 2][lane] + po[XL][wv * 4 + 3][lane];
        const float rv = fmaxf(ob + v, 0.f);
        if ((up >> 8) == bv0) acc0 += rv; else acc1 += rv;
    }

    // block reduction: 4 waves -> <=2 atomics per block (reuse po[0])
    po[0][wv][lane]     = acc0;   // disjoint from po[1] reads above
    po[0][8 + wv][lane] = acc1;
    __syncthreads();
    if (wv == 0) {
        const float t0 = po[0][0][lane] + po[0][1][lane]
                       + po[0][2][lane] + po[0][3][lane];
        atomicAdd(&out[bv0 * NOUTc + lane], t0);
        const int bvLast = (u_base + UNITS_PER_BLOCK - 1) >> 8;
        if (bvLast != bv0) {
            const float t1 = po[0][8][lane] + po[0][9][lane]
                           + po[0][10][lane] + po[0][11][lane];
            atomicAdd(&out[(bv0 + 1) * NOUTc + lane], t1);
        }
    }
}

extern "C" void kernel_launch(void* const* d_in, const int* in_sizes, int n_in,
                              void* d_out, int out_size, void* d_ws, size_t ws_size,
                              hipStream_t stream) {
    const float* src    = (const float*)d_in[0];  // source_embed
    const float* rel    = (const float*)d_in[1];  // rel_index
    // d_in[2] = s        (cancels in softmax)
    const float* W_rel  = (const float*)d_in[3];
    const float* attn_w = (const float*)d_in[4];
    // d_in[5] = attn_b   (cancels in softmax)
    const float* out_w  = (const float*)d_in[6];
    const float* out_b  = (const float*)d_in[7];
    float* out   = (float*)d_out;
    float* diagT = (float*)d_ws;                  // R*D floats = 6 KB

    hipMemsetAsync(out, 0, (size_t)out_size * sizeof(float), stream);
    diag_extract<<<(Rc * Dc + 255) / 256, 256, 0, stream>>>(W_rel, diagT);
    gal_kernel<<<NBLOCKS, 256, 0, stream>>>(src, rel, diagT, attn_w, out_w, out_b, out);
}